// Round 16
// baseline (442.844 us; speedup 1.0000x reference)
//
#include <hip/hip_runtime.h>
#include <hip/hip_bf16.h>
#include <math.h>

#define D 256
#define NPROTO 1024
#define NROWS 16384
#define WRr 13
#define WCc 18
#define WJ (WRr * WCc)
#define JSUB 59                    // ceil(WJ/4)
#define MAGIC 0x1357BEEFu

#define WAITVM(N) asm volatile("s_waitcnt vmcnt(" #N ")" ::: "memory")

typedef __attribute__((ext_vector_type(8))) short short8;
typedef __attribute__((ext_vector_type(4))) float f32x4;

__device__ __forceinline__ int swz_key(int row) {
    return (row & 3) ^ ((row >> 2) & 3);
}

__device__ __forceinline__ short f2bf(float f) {
    union { __hip_bfloat16 b; short s; } u;
    u.b = __float2bfloat16(f);
    return u.s;
}

__device__ __forceinline__ void gload_lds16(void* lds, const void* g) {
    __builtin_amdgcn_global_load_lds(
        (const __attribute__((address_space(1))) unsigned*)g,
        (__attribute__((address_space(3))) unsigned*)lds, 16, 0, 0);
}

// ---- hex-grid neighborhood H[i,j], fp32 (proven R13, absmax 4.0) ----
__device__ __forceinline__ float hval(int i, int j) {
    int ri = i >> 5, ci = i & 31;
    int rj = j >> 5, cj = j & 31;
    float xi = (float)ci + 0.5f * (float)(ri & 1);
    float yi = (float)ri * 0.86602540f;
    float xj = (float)cj + 0.5f * (float)(rj & 1);
    float yj = (float)rj * 0.86602540f;
    float dx0 = xi - xj, dy0 = yi - yj;
    const float W = 32.0f;
    const float Hh = 27.7128129f;  // 32*sqrt(3)/2
    float best = 3.4e38f;
#pragma unroll
    for (int sx = -1; sx <= 1; ++sx) {
        float dx = dx0 + (float)sx * W;
#pragma unroll
        for (int sy = -1; sy <= 1; ++sy) {
            float dy = dy0 + (float)sy * Hh;
            float d2 = dx * dx + dy * dy;
            best = fminf(best, d2);
        }
    }
    return __expf(-0.5f * best);
}

// ws layouts (kt-major, slot-swizzled; PROVEN R10/R13), k = kt*32+slot*8+e:
//  XgS short idx = kt*(NROWS*32) + row*32 + ((slot ^ swz_key(row))*8) + e
//  GbS short idx = kt*(NPROTO*32) + i*32  + ((slot ^ swz_key(i))*8) + e

// ---- fused single-dispatch kernel: 1024 blocks, ALL co-resident (4/CU
//      guaranteed by launch_bounds + 33KB LDS) -> flag sync is deadlock-free
//      regardless of dispatch order. Phases per block:
//      A: convert own 16-row X chunk -> XgS (+x2, +out init); release xflag.
//      B: blocks 0..255 run gmat (R13 verbatim) -> GbS/hsum/hp2; release gflag.
//      C: acquire-spin 8 xflags (n0 group) + 32 gflags (ib0 slice).
//      D: som8 8-phase counted-vmcnt MFMA loop (R13 verbatim).
//      Flags: MAGIC != 0xAA poison; stale-MAGIC on replays is benign because
//      rewrites carry identical bytes (deterministic inputs). ----
__global__ void __launch_bounds__(256, 4) fused_kernel(
    const float* __restrict__ X, const float* __restrict__ P,
    short* __restrict__ XgS, short* __restrict__ GbS,
    float* __restrict__ x2, float* __restrict__ hsum, float* __restrict__ hp2,
    unsigned* __restrict__ gf, unsigned* __restrict__ xf,
    unsigned* __restrict__ out) {
    __shared__ __align__(16) union ShMem {
        struct {
            short Xs[2][128 * 32];   // 8KB each
            short Gs[2][128 * 32];
            float red[2][128];
        } b;                          // 33KB (som)
        struct {
            float ht[4][WJ];
            int jrow[WJ];
            float gpart[4][4][256];
            float hqred[4][4];
            float hsred[4][4];
        } a;                          // 21.2KB (gmat)
    } sh;

    const int t = threadIdx.x;
    const int bid = blockIdx.x;
    const int wsw = ((bid & 7) << 7) | (bid >> 3);  // XCD-bijective tile id
    const int n0 = (wsw >> 3) * 128;
    const int ib0 = (wsw & 7) * 128;
    const int cbase = n0 + (wsw & 7) * 16;          // this block's X chunk

    // ================ A: convert 16 X rows -> XgS, x2, out init ============
    {
        int r = t >> 4, c = t & 15;   // row in chunk, 64B column chunk
        int row = cbase + r;
        const f32x4* src = reinterpret_cast<const f32x4*>(X + (size_t)row * D + c * 16);
        f32x4 v0 = src[0], v1 = src[1], v2 = src[2], v3 = src[3];
        float sq = v0[0]*v0[0]+v0[1]*v0[1]+v0[2]*v0[2]+v0[3]*v0[3]
                 + v1[0]*v1[0]+v1[1]*v1[1]+v1[2]*v1[2]+v1[3]*v1[3]
                 + v2[0]*v2[0]+v2[1]*v2[1]+v2[2]*v2[2]+v2[3]*v2[3]
                 + v3[0]*v3[0]+v3[1]*v3[1]+v3[2]*v3[2]+v3[3]*v3[3];
        sq += __shfl_xor(sq, 1);
        sq += __shfl_xor(sq, 2);
        sq += __shfl_xor(sq, 4);
        sq += __shfl_xor(sq, 8);
        if (c == 0) x2[row] = sq;
        short8 w0, w1;
        w0[0]=f2bf(v0[0]); w0[1]=f2bf(v0[1]); w0[2]=f2bf(v0[2]); w0[3]=f2bf(v0[3]);
        w0[4]=f2bf(v1[0]); w0[5]=f2bf(v1[1]); w0[6]=f2bf(v1[2]); w0[7]=f2bf(v1[3]);
        w1[0]=f2bf(v2[0]); w1[1]=f2bf(v2[1]); w1[2]=f2bf(v2[2]); w1[3]=f2bf(v2[3]);
        w1[4]=f2bf(v3[0]); w1[5]=f2bf(v3[1]); w1[6]=f2bf(v3[2]); w1[7]=f2bf(v3[3]);
        int kt = c >> 1, s0 = (c & 1) * 2, key = swz_key(row);
        short* dst = XgS + (size_t)kt * (NROWS * 32) + (size_t)row * 32;
        *reinterpret_cast<short8*>(dst + ((s0 ^ key) << 3)) = w0;
        *reinterpret_cast<short8*>(dst + (((s0 + 1) ^ key) << 3)) = w1;
        if (t < 16) out[cbase + t] = 0x7f800000u;  // +inf
    }
    __syncthreads();
    if (t == 0) {
        __threadfence();
        __hip_atomic_store(&xf[wsw], MAGIC, __ATOMIC_RELEASE, __HIP_MEMORY_SCOPE_AGENT);
    }

    // ================ B: gmat on carrier blocks (R13 verbatim) =============
    if (bid < 256) {
        int i0 = bid * 4;
        int r0 = i0 >> 5, c0 = i0 & 31;

        for (int u = t; u < WJ; u += 256) {
            int jr = (r0 + (u / WCc) - 6 + 32) & 31;
            int jc = (c0 + (u % WCc) - 7 + 32) & 31;
            int j = jr * 32 + jc;
            sh.a.jrow[u] = j;
#pragma unroll
            for (int s = 0; s < 4; ++s) sh.a.ht[s][u] = hval(i0 + s, j);
        }
        __syncthreads();

        int wv = t >> 6, lane = t & 63;
        int j0 = wv * JSUB;
        int j1 = (j0 + JSUB < WJ) ? j0 + JSUB : WJ;
        f32x4 g[4] = {{0.f,0.f,0.f,0.f},{0.f,0.f,0.f,0.f},{0.f,0.f,0.f,0.f},{0.f,0.f,0.f,0.f}};
        float hqp[4] = {0.f,0.f,0.f,0.f};
        float hsp[4] = {0.f,0.f,0.f,0.f};
        for (int u = j0; u < j1; ++u) {
            f32x4 pv = *reinterpret_cast<const f32x4*>(P + (size_t)sh.a.jrow[u] * D + lane * 4);
            float q = pv[0]*pv[0] + pv[1]*pv[1] + pv[2]*pv[2] + pv[3]*pv[3];
#pragma unroll
            for (int s = 0; s < 4; ++s) {
                float h = sh.a.ht[s][u];
                g[s][0] = fmaf(h, pv[0], g[s][0]);
                g[s][1] = fmaf(h, pv[1], g[s][1]);
                g[s][2] = fmaf(h, pv[2], g[s][2]);
                g[s][3] = fmaf(h, pv[3], g[s][3]);
                hqp[s] = fmaf(h, q, hqp[s]);
                hsp[s] += h;  // lane-uniform
            }
        }
#pragma unroll
        for (int s = 0; s < 4; ++s)
            *reinterpret_cast<f32x4*>(&sh.a.gpart[wv][s][lane * 4]) = g[s];
#pragma unroll
        for (int s = 0; s < 4; ++s) {
#pragma unroll
            for (int off = 1; off < 64; off <<= 1) hqp[s] += __shfl_xor(hqp[s], off);
        }
        if (lane == 0) {
#pragma unroll
            for (int s = 0; s < 4; ++s) { sh.a.hqred[wv][s] = hqp[s]; sh.a.hsred[wv][s] = hsp[s]; }
        }
        __syncthreads();

        {
            int s = t >> 6;
            f32x4 gs = *reinterpret_cast<const f32x4*>(&sh.a.gpart[0][s][lane * 4]);
#pragma unroll
            for (int ww = 1; ww < 4; ++ww) {
                f32x4 gp = *reinterpret_cast<const f32x4*>(&sh.a.gpart[ww][s][lane * 4]);
                gs[0] += gp[0]; gs[1] += gp[1]; gs[2] += gp[2]; gs[3] += gp[3];
            }
            float h0 = __shfl_down(gs[0], 1);
            float h1 = __shfl_down(gs[1], 1);
            float h2 = __shfl_down(gs[2], 1);
            float h3 = __shfl_down(gs[3], 1);
            if (!(lane & 1)) {
                int c = lane >> 1;   // 16B chunk: k = c*8..+7
                int kt = c >> 2;
                int slot = c & 3;
                int i = i0 + s;
                short8 wv8;
                wv8[0]=f2bf(gs[0]); wv8[1]=f2bf(gs[1]); wv8[2]=f2bf(gs[2]); wv8[3]=f2bf(gs[3]);
                wv8[4]=f2bf(h0);    wv8[5]=f2bf(h1);    wv8[6]=f2bf(h2);    wv8[7]=f2bf(h3);
                *reinterpret_cast<short8*>(
                    GbS + (size_t)kt * (NPROTO * 32) + (size_t)i * 32 +
                    ((slot ^ swz_key(i)) << 3)) = wv8;
            }
        }
        if (t < 4) {
            hsum[i0 + t] = sh.a.hsred[0][t] + sh.a.hsred[1][t] + sh.a.hsred[2][t] + sh.a.hsred[3][t];
        } else if (t < 8) {
            int s = t - 4;
            hp2[i0 + s] = sh.a.hqred[0][s] + sh.a.hqred[1][s] + sh.a.hqred[2][s] + sh.a.hqred[3][s];
        }
        __syncthreads();
        if (t == 0) {
            __threadfence();
            __hip_atomic_store(&gf[bid], MAGIC, __ATOMIC_RELEASE, __HIP_MEMORY_SCOPE_AGENT);
        }
    }

    // ================ C: acquire-spin on producers ========================
    if (t < 8) {
        unsigned idx = (unsigned)((wsw & ~7) + t);   // 8 X chunks of my n0 group
        while (__hip_atomic_load(&xf[idx], __ATOMIC_ACQUIRE, __HIP_MEMORY_SCOPE_AGENT) != MAGIC)
            __builtin_amdgcn_s_sleep(16);
    } else if (t < 40) {
        unsigned idx = (unsigned)((ib0 >> 2) + (t - 8));  // 32 gmat carriers of my i slice
        while (__hip_atomic_load(&gf[idx], __ATOMIC_ACQUIRE, __HIP_MEMORY_SCOPE_AGENT) != MAGIC)
            __builtin_amdgcn_s_sleep(16);
    }
    __syncthreads();

    // ================ D: som8 MFMA loop (R13 verbatim) ====================
    const int lane = t & 63;
    const int wid = t >> 6;
    const int wr = wid >> 1;   // n half (64 rows)
    const int wc = wid & 1;    // i half (64 cols)
    const int lm = lane & 15;
    const int lq = lane >> 4;
    const int key = (lm & 3) ^ ((lm >> 2) & 3);

    f32x4 acc[4][4];
#pragma unroll
    for (int m = 0; m < 4; ++m)
#pragma unroll
        for (int n = 0; n < 4; ++n) acc[m][n] = (f32x4){0.f, 0.f, 0.f, 0.f};

    auto stage = [&](int b, int kt) {
#pragma unroll
        for (int q = 0; q < 2; ++q)
            gload_lds16((char*)(&sh.b.Xs[b][0]) + q * 4096 + t * 16,
                        XgS + (size_t)kt * (NROWS * 32) +
                        (size_t)(n0 + q * 64 + (t >> 2)) * 32 + ((t & 3) << 3));
#pragma unroll
        for (int q = 0; q < 2; ++q)
            gload_lds16((char*)(&sh.b.Gs[b][0]) + q * 4096 + t * 16,
                        GbS + (size_t)kt * (NPROTO * 32) +
                        (size_t)(ib0 + q * 64 + (t >> 2)) * 32 + ((t & 3) << 3));
    };

    stage(0, 0);  // 4 VMEM outstanding

#pragma unroll
    for (int p = 0; p < 8; ++p) {
        if (p < 7) stage((p + 1) & 1, p + 1);          // +4 -> 8 outstanding
        if (p < 7) { WAITVM(4); } else { WAITVM(0); }  // retire phase-p stage
        __builtin_amdgcn_sched_barrier(0);
        __builtin_amdgcn_s_barrier();

        const short* xb = &sh.b.Xs[p & 1][0];
        const short* gb = &sh.b.Gs[p & 1][0];
        const int so = (lq ^ key) << 3;
        short8 a[4], b[4];
#pragma unroll
        for (int m = 0; m < 4; ++m)
            a[m] = *reinterpret_cast<const short8*>(&xb[(wr * 64 + m * 16 + lm) * 32 + so]);
#pragma unroll
        for (int n = 0; n < 4; ++n)
            b[n] = *reinterpret_cast<const short8*>(&gb[(wc * 64 + n * 16 + lm) * 32 + so]);
        __builtin_amdgcn_s_setprio(1);
#pragma unroll
        for (int m = 0; m < 4; ++m)
#pragma unroll
            for (int n = 0; n < 4; ++n)
                acc[m][n] = __builtin_amdgcn_mfma_f32_16x16x32_bf16(a[m], b[n], acc[m][n], 0, 0, 0);
        __builtin_amdgcn_s_setprio(0);
        __builtin_amdgcn_s_barrier();
    }

    // ---- epilogue: e = hsum*x2 + hp2 - 2*acc; min over block's 128 i ----
    float x2v[4][4];
#pragma unroll
    for (int m = 0; m < 4; ++m)
#pragma unroll
        for (int j = 0; j < 4; ++j)
            x2v[m][j] = x2[n0 + wr * 64 + m * 16 + lq * 4 + j];

    float rmin[4][4];
#pragma unroll
    for (int m = 0; m < 4; ++m)
#pragma unroll
        for (int j = 0; j < 4; ++j) rmin[m][j] = 3.4e38f;

#pragma unroll
    for (int ni = 0; ni < 4; ++ni) {
        int ig = ib0 + wc * 64 + ni * 16 + lm;
        float hs = hsum[ig];
        float hq = hp2[ig];
#pragma unroll
        for (int m = 0; m < 4; ++m)
#pragma unroll
            for (int j = 0; j < 4; ++j) {
                float e = fmaf(hs, x2v[m][j], hq) - 2.0f * acc[m][ni][j];
                rmin[m][j] = fminf(rmin[m][j], e);
            }
    }

#pragma unroll
    for (int m = 0; m < 4; ++m)
#pragma unroll
        for (int j = 0; j < 4; ++j) {
            float v = rmin[m][j];
            v = fminf(v, __shfl_xor(v, 1));
            v = fminf(v, __shfl_xor(v, 2));
            v = fminf(v, __shfl_xor(v, 4));
            v = fminf(v, __shfl_xor(v, 8));
            rmin[m][j] = v;
        }
    if (lm == 0) {
#pragma unroll
        for (int m = 0; m < 4; ++m)
#pragma unroll
            for (int j = 0; j < 4; ++j)
                sh.b.red[wc][wr * 64 + m * 16 + lq * 4 + j] = rmin[m][j];
    }
    __syncthreads();
    if (t < 128) {
        float v = fminf(sh.b.red[0][t], sh.b.red[1][t]);
        atomicMin(out + n0 + t, __float_as_uint(0.5f * v));
    }
}

extern "C" void kernel_launch(void* const* d_in, const int* in_sizes, int n_in,
                              void* d_out, int out_size, void* d_ws, size_t ws_size,
                              hipStream_t stream) {
    const float* X = (const float*)d_in[0];  // [16384, 256]
    const float* P = (const float*)d_in[1];  // [1024, 256]
    unsigned* out = (unsigned*)d_out;        // [1, 16384] f32 as uint
    (void)in_sizes; (void)n_in; (void)out_size; (void)ws_size;

    float* ws = (float*)d_ws;
    float* hsum = ws + 1024;                 // 1024 f32
    float* hp2 = ws + 2048;                  // 1024 f32
    float* x2 = ws + 4096;                   // 16384 f32 (ends 20480)
    unsigned* gf = (unsigned*)(ws + 20480);  // 256 flags
    unsigned* xf = (unsigned*)(ws + 21504);  // 1024 flags
    short* GbS = (short*)(ws + 32768);       // 512KB, kt-major swizzled
    short* XgS = (short*)(ws + 262144);      // 8.4MB, kt-major swizzled

    fused_kernel<<<1024, 256, 0, stream>>>(X, P, XgS, GbS, x2, hsum, hp2, gf, xf, out);
}

// Round 17
// 33.896 us; speedup vs baseline: 13.0646x; 13.0646x over previous
//
#include <hip/hip_runtime.h>
#include <hip/hip_bf16.h>
#include <math.h>

#define D 256
#define NPROTO 1024
#define NROWS 16384
#define WRr 13
#define WCc 18
#define WJ (WRr * WCc)
#define JSUB 59                    // ceil(WJ/4)
#define GMAT_BLOCKS (NPROTO / 4)   // 256
#define XPREP_BLOCKS (NROWS / 32)  // 512

#define WAITVM(N) asm volatile("s_waitcnt vmcnt(" #N ")" ::: "memory")

typedef __attribute__((ext_vector_type(8))) short short8;
typedef __attribute__((ext_vector_type(4))) float f32x4;

// slot-swizzle key for 64-byte rows (4 slots of 16B); same key on write and
// read (rule 21). 2-way max bank aliasing (free, m136).
__device__ __forceinline__ int swz_key(int row) {
    return (row & 3) ^ ((row >> 2) & 3);
}

__device__ __forceinline__ short f2bf(float f) {
    union { __hip_bfloat16 b; short s; } u;
    u.b = __float2bfloat16(f);
    return u.s;
}

__device__ __forceinline__ void gload_lds16(void* lds, const void* g) {
    __builtin_amdgcn_global_load_lds(
        (const __attribute__((address_space(1))) unsigned*)g,
        (__attribute__((address_space(3))) unsigned*)lds, 16, 0, 0);
}

// ---- hex-grid neighborhood H[i,j], fp32 (proven R13, absmax 4.0) ----
__device__ __forceinline__ float hval(int i, int j) {
    int ri = i >> 5, ci = i & 31;
    int rj = j >> 5, cj = j & 31;
    float xi = (float)ci + 0.5f * (float)(ri & 1);
    float yi = (float)ri * 0.86602540f;
    float xj = (float)cj + 0.5f * (float)(rj & 1);
    float yj = (float)rj * 0.86602540f;
    float dx0 = xi - xj, dy0 = yi - yj;
    const float W = 32.0f;
    const float Hh = 27.7128129f;  // 32*sqrt(3)/2
    float best = 3.4e38f;
#pragma unroll
    for (int sx = -1; sx <= 1; ++sx) {
        float dx = dx0 + (float)sx * W;
#pragma unroll
        for (int sy = -1; sy <= 1; ++sy) {
            float dy = dy0 + (float)sy * Hh;
            float d2 = dx * dx + dy * dy;
            best = fminf(best, d2);
        }
    }
    return __expf(-0.5f * best);
}

// ws layouts (kt-major, slot-swizzled), k = kt*32 + slot*8 + e:
//  XgS short idx = kt*(NROWS*32) + row*32 + ((slot ^ swz_key(row))*8) + e
//  GbS short idx = kt*(NPROTO*32) + i*32  + ((slot ^ swz_key(i))*8) + e

// ---- prep (R13 verbatim): role-split.
//  bx < 256:   gmat -> GbS + hsum + hp2
//  bx >= 256:  xprep -> XgS + x2 + out=+inf (XCD-aligned base) ----
__global__ void __launch_bounds__(256) prep_kernel(
    const float* __restrict__ X, const float* __restrict__ P,
    short* __restrict__ XgS, short* __restrict__ GbS,
    float* __restrict__ x2, float* __restrict__ hsum, float* __restrict__ hp2,
    unsigned* __restrict__ out) {
    int t = threadIdx.x;
    int bx = blockIdx.x;

    if (bx >= GMAT_BLOCKS) {
        // ---------------- xprep: 32 rows, XCD-aligned base ----------------
        int xb = bx - GMAT_BLOCKS;
        int base0 = (xb & 7) * 2048 + (xb >> 3) * 32;
        int g = t & 31;          // k-chunk: k = g*8..+7
        int kt = g >> 2;
        int slot = g & 3;
#pragma unroll
        for (int it = 0; it < 4; ++it) {
            int row = base0 + it * 8 + (t >> 5);
            const float4* src = reinterpret_cast<const float4*>(X + (size_t)row * D) + g * 2;
            float4 a = src[0], b = src[1];
            float s = a.x * a.x + a.y * a.y + a.z * a.z + a.w * a.w +
                      b.x * b.x + b.y * b.y + b.z * b.z + b.w * b.w;
            s += __shfl_xor(s, 1);
            s += __shfl_xor(s, 2);
            s += __shfl_xor(s, 4);
            s += __shfl_xor(s, 8);
            s += __shfl_xor(s, 16);
            if (g == 0) x2[row] = s;
            short8 w;
            w[0] = f2bf(a.x); w[1] = f2bf(a.y); w[2] = f2bf(a.z); w[3] = f2bf(a.w);
            w[4] = f2bf(b.x); w[5] = f2bf(b.y); w[6] = f2bf(b.z); w[7] = f2bf(b.w);
            *reinterpret_cast<short8*>(
                XgS + (size_t)kt * (NROWS * 32) + (size_t)row * 32 +
                ((slot ^ swz_key(row)) << 3)) = w;
        }
        if (t < 32) out[base0 + t] = 0x7f800000u;  // +inf
        return;
    }

    // ---------------- gmat ----------------
    __shared__ float ht[4][WJ];
    __shared__ int jrow[WJ];
    __shared__ __align__(16) float gpart[4][4][256];
    __shared__ float hqred[4][4];
    __shared__ float hsred[4][4];
    int i0 = bx * 4;
    int r0 = i0 >> 5, c0 = i0 & 31;

    for (int u = t; u < WJ; u += 256) {
        int jr = (r0 + (u / WCc) - 6 + 32) & 31;
        int jc = (c0 + (u % WCc) - 7 + 32) & 31;
        int j = jr * 32 + jc;
        jrow[u] = j;
#pragma unroll
        for (int s = 0; s < 4; ++s) ht[s][u] = hval(i0 + s, j);
    }
    __syncthreads();

    int w = t >> 6, lane = t & 63;
    int j0 = w * JSUB;
    int j1 = (j0 + JSUB < WJ) ? j0 + JSUB : WJ;
    f32x4 g[4] = {{0.f, 0.f, 0.f, 0.f}, {0.f, 0.f, 0.f, 0.f},
                  {0.f, 0.f, 0.f, 0.f}, {0.f, 0.f, 0.f, 0.f}};
    float hqp[4] = {0.f, 0.f, 0.f, 0.f};
    float hsp[4] = {0.f, 0.f, 0.f, 0.f};
    for (int u = j0; u < j1; ++u) {
        f32x4 pv = *reinterpret_cast<const f32x4*>(P + (size_t)jrow[u] * D + lane * 4);
        float q = pv[0] * pv[0] + pv[1] * pv[1] + pv[2] * pv[2] + pv[3] * pv[3];
#pragma unroll
        for (int s = 0; s < 4; ++s) {
            float h = ht[s][u];
            g[s][0] = fmaf(h, pv[0], g[s][0]);
            g[s][1] = fmaf(h, pv[1], g[s][1]);
            g[s][2] = fmaf(h, pv[2], g[s][2]);
            g[s][3] = fmaf(h, pv[3], g[s][3]);
            hqp[s] = fmaf(h, q, hqp[s]);
            hsp[s] += h;  // lane-uniform
        }
    }
#pragma unroll
    for (int s = 0; s < 4; ++s)
        *reinterpret_cast<f32x4*>(&gpart[w][s][lane * 4]) = g[s];
#pragma unroll
    for (int s = 0; s < 4; ++s) {
#pragma unroll
        for (int off = 1; off < 64; off <<= 1) hqp[s] += __shfl_xor(hqp[s], off);
    }
    if (lane == 0) {
#pragma unroll
        for (int s = 0; s < 4; ++s) { hqred[w][s] = hqp[s]; hsred[w][s] = hsp[s]; }
    }
    __syncthreads();

    {
        int s = t >> 6;
        f32x4 gs = *reinterpret_cast<const f32x4*>(&gpart[0][s][lane * 4]);
#pragma unroll
        for (int ww = 1; ww < 4; ++ww) {
            f32x4 gp = *reinterpret_cast<const f32x4*>(&gpart[ww][s][lane * 4]);
            gs[0] += gp[0]; gs[1] += gp[1]; gs[2] += gp[2]; gs[3] += gp[3];
        }
        float h0 = __shfl_down(gs[0], 1);
        float h1 = __shfl_down(gs[1], 1);
        float h2 = __shfl_down(gs[2], 1);
        float h3 = __shfl_down(gs[3], 1);
        if (!(lane & 1)) {
            int c = lane >> 1;   // 16B chunk: k = c*8..+7
            int kt = c >> 2;
            int slot = c & 3;
            int i = i0 + s;
            short8 wv;
            wv[0] = f2bf(gs[0]); wv[1] = f2bf(gs[1]); wv[2] = f2bf(gs[2]); wv[3] = f2bf(gs[3]);
            wv[4] = f2bf(h0);    wv[5] = f2bf(h1);    wv[6] = f2bf(h2);    wv[7] = f2bf(h3);
            *reinterpret_cast<short8*>(
                GbS + (size_t)kt * (NPROTO * 32) + (size_t)i * 32 +
                ((slot ^ swz_key(i)) << 3)) = wv;
        }
    }
    if (t < 4) {
        hsum[i0 + t] = hsred[0][t] + hsred[1][t] + hsred[2][t] + hsred[3][t];
    } else if (t < 8) {
        int s = t - 4;
        hp2[i0 + s] = hqred[0][s] + hqred[1][s] + hqred[2][s] + hqred[3][s];
    }
}

// ---- som17: R13's som8 with a 3-BUFFER, 2-phase-deep prefetch pipeline.
//      Phase p: issue stage(p+2); vmcnt(8) retires only stage(p) (oldest) ->
//      every buffer gets ~2 full phases (~600-1000cyc) to land, covering
//      cold-L3 latency. LDS 49KB -> 3 blocks/CU (12 waves). ----
__global__ void __launch_bounds__(256, 3) som17_kernel(
    const short* __restrict__ XgS, const short* __restrict__ GbS,
    const float* __restrict__ x2, const float* __restrict__ hsum,
    const float* __restrict__ hp2, unsigned* __restrict__ out) {
    __shared__ __align__(16) short Xs[3][128 * 32];  // 8KB each
    __shared__ __align__(16) short Gs[3][128 * 32];
    __shared__ float red[2][128];

    const int t = threadIdx.x;
    const int lane = t & 63;
    const int wid = t >> 6;
    const int wr = wid >> 1;   // n half (64 rows)
    const int wc = wid & 1;    // i half (64 cols)
    const int lm = lane & 15;
    const int lq = lane >> 4;
    const int key = (lm & 3) ^ ((lm >> 2) & 3);

    // XCD-bijective swizzle: 1024 blocks = 8 XCDs x 128
    const int lin = blockIdx.x;
    const int w1024 = ((lin & 7) << 7) | (lin >> 3);
    const int n0 = (w1024 >> 3) * 128;
    const int ib0 = (w1024 & 7) * 128;

    f32x4 acc[4][4];
#pragma unroll
    for (int m = 0; m < 4; ++m)
#pragma unroll
        for (int n = 0; n < 4; ++n) acc[m][n] = (f32x4){0.f, 0.f, 0.f, 0.f};

    auto stage = [&](int b, int kt) {
        // linear dest; sources pre-swizzled in ws -> contiguous reads
#pragma unroll
        for (int q = 0; q < 2; ++q)
            gload_lds16((char*)(&Xs[b][0]) + q * 4096 + t * 16,
                        XgS + (size_t)kt * (NROWS * 32) +
                        (size_t)(n0 + q * 64 + (t >> 2)) * 32 + ((t & 3) << 3));
#pragma unroll
        for (int q = 0; q < 2; ++q)
            gload_lds16((char*)(&Gs[b][0]) + q * 4096 + t * 16,
                        GbS + (size_t)kt * (NPROTO * 32) +
                        (size_t)(ib0 + q * 64 + (t >> 2)) * 32 + ((t & 3) << 3));
    };

    // prologue: 2 stages in flight (8 VMEM)
    stage(0, 0);
    stage(1, 1);

#pragma unroll
    for (int p = 0; p < 8; ++p) {
        if (p < 6) stage((p + 2) % 3, p + 2);   // 12 outstanding
        // retire only the OLDEST stage (the one this phase computes on):
        if (p < 6) { WAITVM(8); }
        else if (p == 6) { WAITVM(4); }
        else { WAITVM(0); }
        __builtin_amdgcn_sched_barrier(0);
        __builtin_amdgcn_s_barrier();

        const short* xb = &Xs[p % 3][0];
        const short* gb = &Gs[p % 3][0];
        const int so = (lq ^ key) << 3;
        short8 a[4], b[4];
#pragma unroll
        for (int m = 0; m < 4; ++m)
            a[m] = *reinterpret_cast<const short8*>(&xb[(wr * 64 + m * 16 + lm) * 32 + so]);
#pragma unroll
        for (int n = 0; n < 4; ++n)
            b[n] = *reinterpret_cast<const short8*>(&gb[(wc * 64 + n * 16 + lm) * 32 + so]);
        __builtin_amdgcn_s_setprio(1);
#pragma unroll
        for (int m = 0; m < 4; ++m)
#pragma unroll
            for (int n = 0; n < 4; ++n)
                acc[m][n] = __builtin_amdgcn_mfma_f32_16x16x32_bf16(a[m], b[n], acc[m][n], 0, 0, 0);
        __builtin_amdgcn_s_setprio(0);
        __builtin_amdgcn_s_barrier();
    }

    // ---- epilogue: e = hsum*x2 + hp2 - 2*acc; min over block's 128 i ----
    float x2v[4][4];
#pragma unroll
    for (int m = 0; m < 4; ++m)
#pragma unroll
        for (int j = 0; j < 4; ++j)
            x2v[m][j] = x2[n0 + wr * 64 + m * 16 + lq * 4 + j];

    float rmin[4][4];
#pragma unroll
    for (int m = 0; m < 4; ++m)
#pragma unroll
        for (int j = 0; j < 4; ++j) rmin[m][j] = 3.4e38f;

#pragma unroll
    for (int ni = 0; ni < 4; ++ni) {
        int ig = ib0 + wc * 64 + ni * 16 + lm;
        float hs = hsum[ig];
        float hq = hp2[ig];
#pragma unroll
        for (int m = 0; m < 4; ++m)
#pragma unroll
            for (int j = 0; j < 4; ++j) {
                float e = fmaf(hs, x2v[m][j], hq) - 2.0f * acc[m][ni][j];
                rmin[m][j] = fminf(rmin[m][j], e);
            }
    }

#pragma unroll
    for (int m = 0; m < 4; ++m)
#pragma unroll
        for (int j = 0; j < 4; ++j) {
            float v = rmin[m][j];
            v = fminf(v, __shfl_xor(v, 1));
            v = fminf(v, __shfl_xor(v, 2));
            v = fminf(v, __shfl_xor(v, 4));
            v = fminf(v, __shfl_xor(v, 8));
            rmin[m][j] = v;
        }
    if (lm == 0) {
#pragma unroll
        for (int m = 0; m < 4; ++m)
#pragma unroll
            for (int j = 0; j < 4; ++j)
                red[wc][wr * 64 + m * 16 + lq * 4 + j] = rmin[m][j];
    }
    __syncthreads();
    if (t < 128) {
        float v = fminf(red[0][t], red[1][t]);
        atomicMin(out + n0 + t, __float_as_uint(0.5f * v));
    }
}

extern "C" void kernel_launch(void* const* d_in, const int* in_sizes, int n_in,
                              void* d_out, int out_size, void* d_ws, size_t ws_size,
                              hipStream_t stream) {
    const float* X = (const float*)d_in[0];  // [16384, 256]
    const float* P = (const float*)d_in[1];  // [1024, 256]
    unsigned* out = (unsigned*)d_out;        // [1, 16384] f32 as uint
    (void)in_sizes; (void)n_in; (void)out_size; (void)ws_size;

    float* ws = (float*)d_ws;
    float* hsum = ws + 1024;             // 1024 f32
    float* hp2 = ws + 2048;              // 1024 f32
    float* x2 = ws + 4096;               // 16384 f32
    short* GbS = (short*)(ws + 32768);   // 1024*256 bf16 kt-major swizzled (512KB)
    short* XgS = (short*)(ws + 262144);  // 16384*256 bf16 kt-major swizzled (8.4MB)

    prep_kernel<<<GMAT_BLOCKS + XPREP_BLOCKS, 256, 0, stream>>>(
        X, P, XgS, GbS, x2, hsum, hp2, out);
    som17_kernel<<<1024, 256, 0, stream>>>(XgS, GbS, x2, hsum, hp2, out);
}